// Round 1
// baseline (253.543 us; speedup 1.0000x reference)
//
#include <hip/hip_runtime.h>

// ParallelLinear: out[b,t,o] = sum_i x[b,t,i] * W[t,o,i] + bias[t,o]
// B=512, T=1024, ISIZE=OSIZE=64, all fp32.
//
// Block = 256 threads, handles one t and 64 rows of B.
// LDS: W[t] transposed (Wt[i][o], pitch 68), X tile natural (Xs[r][i], pitch 68).
// Each thread computes a 4x4 output tile; K-loop of 64.

#define T_DIM 1024
#define B_DIM 512
#define KSZ 64
#define OSZ 64
#define ROWS 64
#define PITCH 68   // 64 + 4: keeps float4 alignment, breaks pow2 bank stride

__global__ __launch_bounds__(256, 4) void pl_kernel(
    const float* __restrict__ x,
    const float* __restrict__ W,
    const float* __restrict__ bias,
    float* __restrict__ out)
{
    __shared__ float Wt[KSZ * PITCH];    // Wt[i*PITCH + o] = W[t][o][i]
    __shared__ float Xs[ROWS * PITCH];   // Xs[r*PITCH + i] = x[row0+r][t][i]

    const int t     = blockIdx.x >> 3;   // 0..1023
    const int chunk = blockIdx.x & 7;    // 0..7
    const int row0  = chunk * ROWS;      // base b index
    const int tid   = threadIdx.x;

    // ---- stage W[t] (4096 floats) transposed into LDS ----
    const float4* Wg = (const float4*)(W + (size_t)t * (OSZ * KSZ));
    #pragma unroll
    for (int j = 0; j < 4; ++j) {
        int idx = tid + j * 256;         // float4 index 0..1023
        int o   = idx >> 4;              // 0..63
        int i0  = (idx & 15) << 2;       // 0,4,...,60
        float4 wv = Wg[idx];
        Wt[(i0 + 0) * PITCH + o] = wv.x;
        Wt[(i0 + 1) * PITCH + o] = wv.y;
        Wt[(i0 + 2) * PITCH + o] = wv.z;
        Wt[(i0 + 3) * PITCH + o] = wv.w;
    }

    // ---- stage X tile: 64 rows x 64 floats; one wave reads 4 complete rows ----
    #pragma unroll
    for (int it = 0; it < 4; ++it) {
        int r  = (tid >> 4) + it * 16;   // local row 0..63
        int i0 = (tid & 15) << 2;        // 0,4,...,60
        const float4* xg = (const float4*)(x + ((size_t)(row0 + r) * T_DIM + t) * KSZ + i0);
        float4 xv = *xg;
        *(float4*)&Xs[r * PITCH + i0] = xv;
    }

    __syncthreads();

    // ---- compute: thread (tr,tc) does rows 4tr..4tr+3, cols 4tc..4tc+3 ----
    const int tr = tid >> 4;             // 0..15
    const int tc = tid & 15;             // 0..15

    float acc[4][4] = {};

    #pragma unroll 8
    for (int i = 0; i < KSZ; ++i) {
        float4 wv = *(const float4*)&Wt[i * PITCH + (tc << 2)];
        float xk0 = Xs[(tr * 4 + 0) * PITCH + i];
        float xk1 = Xs[(tr * 4 + 1) * PITCH + i];
        float xk2 = Xs[(tr * 4 + 2) * PITCH + i];
        float xk3 = Xs[(tr * 4 + 3) * PITCH + i];
        acc[0][0] += xk0 * wv.x; acc[0][1] += xk0 * wv.y; acc[0][2] += xk0 * wv.z; acc[0][3] += xk0 * wv.w;
        acc[1][0] += xk1 * wv.x; acc[1][1] += xk1 * wv.y; acc[1][2] += xk1 * wv.z; acc[1][3] += xk1 * wv.w;
        acc[2][0] += xk2 * wv.x; acc[2][1] += xk2 * wv.y; acc[2][2] += xk2 * wv.z; acc[2][3] += xk2 * wv.w;
        acc[3][0] += xk3 * wv.x; acc[3][1] += xk3 * wv.y; acc[3][2] += xk3 * wv.z; acc[3][3] += xk3 * wv.w;
    }

    // ---- epilogue: add bias, store float4 per row ----
    float4 bv = *(const float4*)(bias + (size_t)t * OSZ + (tc << 2));
    #pragma unroll
    for (int k = 0; k < 4; ++k) {
        int b = row0 + tr * 4 + k;
        float4 res;
        res.x = acc[k][0] + bv.x;
        res.y = acc[k][1] + bv.y;
        res.z = acc[k][2] + bv.z;
        res.w = acc[k][3] + bv.w;
        *(float4*)(out + ((size_t)b * T_DIM + t) * OSZ + (tc << 2)) = res;
    }
}

extern "C" void kernel_launch(void* const* d_in, const int* in_sizes, int n_in,
                              void* d_out, int out_size, void* d_ws, size_t ws_size,
                              hipStream_t stream) {
    const float* x    = (const float*)d_in[0];
    const float* W    = (const float*)d_in[1];
    const float* bias = (const float*)d_in[2];
    float* out        = (float*)d_out;

    dim3 grid(T_DIM * (B_DIM / ROWS));   // 8192 blocks
    dim3 block(256);
    pl_kernel<<<grid, block, 0, stream>>>(x, W, bias, out);
}